// Round 1
// baseline (3828.436 us; speedup 1.0000x reference)
//
#include <hip/hip_runtime.h>
#include <hip/hip_bf16.h>

typedef __attribute__((ext_vector_type(8))) short s16x8;
typedef __attribute__((ext_vector_type(4))) float f32x4;

__device__ __forceinline__ ushort f2bf(float x) {
  __hip_bfloat16 b = __float2bfloat16(x);
  return *reinterpret_cast<ushort*>(&b);
}

__device__ __forceinline__ float sigm_fast(float z) {
  // 1/(1+exp(-z)) via exp2/rcp (1-ulp class approx, fine vs 2e-2 threshold)
  return __builtin_amdgcn_rcpf(1.0f + __builtin_amdgcn_exp2f(z * -1.44269504088896f));
}

// ---------------------------------------------------------------------------
// K0: pack weights.
// Packed column index p in [0,2048): q = p>>5 (32-col block), c32 = p&31,
// nt = c32>>4, l15 = c32&15 ->  gate = p&3, hcol = q*8 + nt*4 + (l15>>2).
// Wx[p][k] (bf16, col-major k-contig) = W_gate[k][hcol]          (k<512)
// Rs[p][k]                             = W_gate[512+k][hcol] + R_gate[k][hcol]
// bp[p] = b_gate[hcol]
// ---------------------------------------------------------------------------
__global__ __launch_bounds__(256) void pack_weights(
    const float* __restrict__ Wf, const float* __restrict__ Wi,
    const float* __restrict__ Wg, const float* __restrict__ Wo,
    const float* __restrict__ Rf, const float* __restrict__ Ri,
    const float* __restrict__ Rg, const float* __restrict__ Ro,
    const float* __restrict__ bfp, const float* __restrict__ bip,
    const float* __restrict__ bgp, const float* __restrict__ bop,
    ushort* __restrict__ Wx, ushort* __restrict__ Rs, float* __restrict__ bp)
{
  const int p = blockIdx.x * 8 + (threadIdx.x >> 5);
  const int kk = (threadIdx.x & 31) * 16;
  const int gate = p & 3;
  const int hcol = (p >> 5) * 8 + ((p >> 4) & 1) * 4 + ((p & 15) >> 2);
  const float* W = (gate == 0) ? Wf : (gate == 1) ? Wi : (gate == 2) ? Wg : Wo;
  const float* R = (gate == 0) ? Rf : (gate == 1) ? Ri : (gate == 2) ? Rg : Ro;
  union { ushort u[16]; s16x8 v[2]; } wb, rb;
#pragma unroll
  for (int e = 0; e < 16; ++e) {
    const int k = kk + e;
    wb.u[e] = f2bf(W[(size_t)k * 512 + hcol]);
    rb.u[e] = f2bf(W[(size_t)(512 + k) * 512 + hcol] + R[(size_t)k * 512 + hcol]);
  }
  *(s16x8*)(Wx + (size_t)p * 512 + kk)     = wb.v[0];
  *(s16x8*)(Wx + (size_t)p * 512 + kk + 8) = wb.v[1];
  *(s16x8*)(Rs + (size_t)p * 512 + kk)     = rb.v[0];
  *(s16x8*)(Rs + (size_t)p * 512 + kk + 8) = rb.v[1];
  if ((threadIdx.x & 31) == 0) {
    const float* B = (gate == 0) ? bfp : (gate == 1) ? bip : (gate == 2) ? bgp : bop;
    bp[p] = B[hcol];
  }
}

// ---------------------------------------------------------------------------
// K1: pre-swizzle x into 16x16x32 A-fragment layout (bf16).
// Frag F = (mt*16 + kc)*64 + lane holds x[t][mt*16 + (lane&15)][kc*32 + (lane>>4)*8 + j]
// xsw[(t*4096 + F)*8 + j]
// ---------------------------------------------------------------------------
__global__ __launch_bounds__(256) void swizzle_x(
    const float* __restrict__ x, ushort* __restrict__ xsw)
{
  __shared__ ushort xl[64 * 520];  // [64 rows][512 + 8 pad]
  const int t = blockIdx.x;
  const int tid = threadIdx.x;
  const float4* x4 = (const float4*)(x + (size_t)t * 32768);
#pragma unroll 4
  for (int j = 0; j < 32; ++j) {
    const int i4 = j * 256 + tid;           // 0..8191
    const float4 v = x4[i4];
    const int base = i4 * 4;
    const int row = base >> 9;
    const int col = base & 511;
    ushort4 u;
    u.x = f2bf(v.x); u.y = f2bf(v.y); u.z = f2bf(v.z); u.w = f2bf(v.w);
    *(ushort4*)(&xl[row * 520 + col]) = u;
  }
  __syncthreads();
#pragma unroll 4
  for (int j = 0; j < 16; ++j) {
    const int F = j * 256 + tid;            // 0..4095
    const int l = F & 63;
    const int kc = (F >> 6) & 15;
    const int mt = F >> 10;
    const int row = mt * 16 + (l & 15);
    const int k0 = kc * 32 + (l >> 4) * 8;
    const s16x8 v = *(const s16x8*)(&xl[row * 520 + k0]);
    *(s16x8*)(&xsw[((size_t)t * 4096 + F) * 8]) = v;
  }
}

// ---------------------------------------------------------------------------
// K2: Zx chunk GEMM: Zx[t] = x_t @ Wx  (bias added in rec kernel).
// Output in C-fragment layout: zx[((tl*4 + mt)*64 + q)*64 + lane)*8 + nt*4 + r]
//   = z[b = mt*16 + (lane>>4)*4 + r][pcol = q*32 + nt*16 + (lane&15)]
// Grid (16 pcol-groups x G t-groups) x 512 thr. Waves: (mpair 0..1, np 0..3),
// q = pg*4+np. B (Wx frags) kept fully in registers (128 VGPR/wave).
// ---------------------------------------------------------------------------
__global__ __launch_bounds__(512, 2) void zx_gemm(
    const ushort* __restrict__ xsw, const ushort* __restrict__ Wx,
    float* __restrict__ zx, int t0, int tcnt)
{
  __shared__ ushort lbuf[32768];  // 64KB: one t's A-fragments
  const int pg = blockIdx.x;
  const int tgrp = blockIdx.y;
  const int tid = threadIdx.x;
  const int wid = tid >> 6;
  const int lane = tid & 63;
  const int mpair = wid >> 2;
  const int np = wid & 3;
  const int q = pg * 4 + np;
  const int l15 = lane & 15;
  const int hi = lane >> 4;

  s16x8 Bg[2][16];
#pragma unroll
  for (int nt = 0; nt < 2; ++nt)
#pragma unroll
    for (int kc = 0; kc < 16; ++kc)
      Bg[nt][kc] = *(const s16x8*)(Wx + (size_t)(q * 32 + nt * 16 + l15) * 512 + kc * 32 + hi * 8);

  for (int tt = 0; tt < tcnt; ++tt) {
    const int tl = tgrp * tcnt + tt;
    const int t = t0 + tl;
    // stage this t's 4096 fragments linearly into LDS
#pragma unroll
    for (int j = 0; j < 8; ++j) {
      const int fid = j * 512 + tid;
      *(s16x8*)(&lbuf[(size_t)fid * 8]) =
          *(const s16x8*)(xsw + ((size_t)t * 4096 + fid) * 8);
    }
    __syncthreads();
#pragma unroll
    for (int a = 0; a < 2; ++a) {
      const int mt = mpair * 2 + a;
      f32x4 acc0 = {0.f, 0.f, 0.f, 0.f};
      f32x4 acc1 = {0.f, 0.f, 0.f, 0.f};
#pragma unroll
      for (int kc = 0; kc < 16; ++kc) {
        const s16x8 af = *(const s16x8*)(&lbuf[((size_t)(mt * 16 + kc) * 64 + lane) * 8]);
        acc0 = __builtin_amdgcn_mfma_f32_16x16x32_bf16(af, Bg[0][kc], acc0, 0, 0, 0);
        acc1 = __builtin_amdgcn_mfma_f32_16x16x32_bf16(af, Bg[1][kc], acc1, 0, 0, 0);
      }
      float* o = zx + ((((size_t)tl * 4 + mt) * 64 + q) * 64 + lane) * 8;
      *(f32x4*)(o)     = acc0;
      *(f32x4*)(o + 4) = acc1;
    }
    __syncthreads();
  }
}

// ---------------------------------------------------------------------------
// K3: recurrence over one chunk of CH steps. 32 WGs x 512 thr (8 waves).
// Wave (m = wid&3 rows m*16.., n = wid>>2), q = blockIdx.x*2+n owns 32 packed
// z-cols. Rsum fragments in registers; h double-buffered bf16 in ws; c in regs.
// Grid barrier: per-WG flag (monotone step count), release/acquire agent scope.
// ---------------------------------------------------------------------------
__global__ __launch_bounds__(512, 2) void rec_kernel(
    const ushort* __restrict__ Rs, const float* __restrict__ bp,
    const float* __restrict__ zx, ushort* __restrict__ hbuf,
    float* __restrict__ csave, int* __restrict__ flags,
    float* __restrict__ dout, int t0, int CH)
{
  const int w = blockIdx.x;
  const int tid = threadIdx.x;
  const int wid = tid >> 6;
  const int lane = tid & 63;
  const int m = wid & 3;
  const int n = wid >> 2;
  const int q = w * 2 + n;
  const int gate = lane & 3;
  const int l15 = lane & 15;
  const int hi = lane >> 4;

  s16x8 Brg[2][16];
#pragma unroll
  for (int nt = 0; nt < 2; ++nt)
#pragma unroll
    for (int kc = 0; kc < 16; ++kc)
      Brg[nt][kc] = *(const s16x8*)(Rs + (size_t)(q * 32 + nt * 16 + l15) * 512 + kc * 32 + hi * 8);

  const float b0 = bp[q * 32 + l15];
  const float b1 = bp[q * 32 + 16 + l15];

  float cst[2][4];
  float* csp = csave + ((size_t)(w * 8 + wid) * 64 + lane) * 8;
  if (t0 == 0) {
#pragma unroll
    for (int i = 0; i < 2; ++i)
#pragma unroll
      for (int r = 0; r < 4; ++r) cst[i][r] = 0.0f;
  } else {
#pragma unroll
    for (int i = 0; i < 2; ++i)
#pragma unroll
      for (int r = 0; r < 4; ++r) cst[i][r] = csp[i * 4 + r];
  }

  const int arow = m * 16 + l15;            // A row this lane loads
  const int srow = m * 16 + hi * 4 + gate;  // output row this lane stores
  const int hcol0 = q * 8 + (l15 >> 2);

  for (int tl = 0; tl < CH; ++tl) {
    const int t = t0 + tl;
    const ushort* hb = hbuf + (size_t)(t & 1) * 32768;
    ushort* hn = hbuf + (size_t)((t + 1) & 1) * 32768;

    // prefetch Zx fragment (fp32, C-layout)
    const float* zp = zx + ((((size_t)tl * 4 + m) * 64 + q) * 64 + lane) * 8;
    const float4 z0 = *(const float4*)zp;
    const float4 z1 = *(const float4*)(zp + 4);

    f32x4 acc0 = {0.f, 0.f, 0.f, 0.f};
    f32x4 acc1 = {0.f, 0.f, 0.f, 0.f};
#pragma unroll
    for (int kc = 0; kc < 16; ++kc) {
      const s16x8 a = *(const s16x8*)(hb + (size_t)arow * 512 + kc * 32 + hi * 8);
      acc0 = __builtin_amdgcn_mfma_f32_16x16x32_bf16(a, Brg[0][kc], acc0, 0, 0, 0);
      acc1 = __builtin_amdgcn_mfma_f32_16x16x32_bf16(a, Brg[1][kc], acc1, 0, 0, 0);
    }

    float h_out[2][4];
#pragma unroll
    for (int nt = 0; nt < 2; ++nt) {
#pragma unroll
      for (int r = 0; r < 4; ++r) {
        float z = (nt ? acc1[r] : acc0[r]);
        z += nt ? ((r == 0) ? z1.x : (r == 1) ? z1.y : (r == 2) ? z1.z : z1.w)
                : ((r == 0) ? z0.x : (r == 1) ? z0.y : (r == 2) ? z0.z : z0.w);
        z += nt ? b1 : b0;
        // this lane's gate activation (gate==2 -> tanh via 2*sig(2z)-1)
        const float zz = (gate == 2) ? z + z : z;
        const float s = sigm_fast(zz);
        const float act = (gate == 2) ? (s + s - 1.0f) : s;
        // quad broadcasts: f,i,g,o for this hcol/rows
        const int ai = __float_as_int(act);
        const float fv = __int_as_float(__builtin_amdgcn_mov_dpp(ai, 0x00, 0xF, 0xF, true));
        const float iv = __int_as_float(__builtin_amdgcn_mov_dpp(ai, 0x55, 0xF, 0xF, true));
        const float gv = __int_as_float(__builtin_amdgcn_mov_dpp(ai, 0xAA, 0xF, 0xF, true));
        const float ov = __int_as_float(__builtin_amdgcn_mov_dpp(ai, 0xFF, 0xF, 0xF, true));
        const float cn = fmaf(fv, cst[nt][r], iv * gv);
        cst[nt][r] = cn;
        const float s2 = sigm_fast(cn + cn);
        h_out[nt][r] = ov * (s2 + s2 - 1.0f);  // o * tanh(c)
      }
    }

    // each lane stores reg r == its gate (rows partitioned across the quad)
#pragma unroll
    for (int nt = 0; nt < 2; ++nt) {
      const float hsel = (gate == 0) ? h_out[nt][0] : (gate == 1) ? h_out[nt][1]
                       : (gate == 2) ? h_out[nt][2] : h_out[nt][3];
      const int hcol = hcol0 + nt * 4;
      hn[(size_t)srow * 512 + hcol] = f2bf(hsel);
      dout[(size_t)t * 32768 + (size_t)srow * 512 + hcol] = hsel;
      if (t == 511) {
        const float csel = (gate == 0) ? cst[nt][0] : (gate == 1) ? cst[nt][1]
                         : (gate == 2) ? cst[nt][2] : cst[nt][3];
        dout[(size_t)16777216 + (size_t)srow * 512 + hcol] = hsel;
        dout[(size_t)16809984 + (size_t)srow * 512 + hcol] = csel;
      }
    }

    if (tl != CH - 1) {
      __syncthreads();  // drains all waves' vmem stores (compiler emits vmcnt(0))
      if (tid == 0)
        __hip_atomic_store(&flags[w], tl + 1, __ATOMIC_RELEASE, __HIP_MEMORY_SCOPE_AGENT);
      if (wid == 0) {
        const int target = tl + 1;
        const int idx = lane & 31;
        bool ok;
        do {
          const int v = __hip_atomic_load(&flags[idx], __ATOMIC_RELAXED, __HIP_MEMORY_SCOPE_AGENT);
          ok = (lane >= 32) || (v >= target);
        } while (!__all(ok));
        __builtin_amdgcn_fence(__ATOMIC_ACQUIRE, "agent");
      }
      __syncthreads();
    }
  }

#pragma unroll
  for (int i = 0; i < 2; ++i)
#pragma unroll
    for (int r = 0; r < 4; ++r) csp[i * 4 + r] = cst[i][r];
}

// ---------------------------------------------------------------------------
extern "C" void kernel_launch(void* const* d_in, const int* in_sizes, int n_in,
                              void* d_out, int out_size, void* d_ws, size_t ws_size,
                              hipStream_t stream)
{
  const float* x   = (const float*)d_in[0];
  const float* Wf  = (const float*)d_in[1];
  const float* bfp = (const float*)d_in[2];
  const float* Wi  = (const float*)d_in[3];
  const float* bip = (const float*)d_in[4];
  const float* Wg  = (const float*)d_in[5];
  const float* bgp = (const float*)d_in[6];
  const float* Wo  = (const float*)d_in[7];
  const float* bop = (const float*)d_in[8];
  const float* Rf  = (const float*)d_in[9];
  const float* Ri  = (const float*)d_in[10];
  const float* Rg  = (const float*)d_in[11];
  const float* Ro  = (const float*)d_in[12];
  float* dout = (float*)d_out;
  char* ws = (char*)d_ws;

  const size_t o_Wx  = 0;
  const size_t o_Rs  = o_Wx + 2097152;       // 2048*512*2
  const size_t o_bp  = o_Rs + 2097152;
  const size_t o_xsw = o_bp + 8192;
  const size_t o_zx  = o_xsw + 33554432;     // 512*4096*8*2

  int CH = 64;  // chunk size in timesteps; shrink if workspace is small
  while (CH > 4) {
    const size_t need = o_zx + (size_t)CH * 524288 + 131072 + 524288 + 256;
    if (need <= ws_size) break;
    CH >>= 1;
  }
  const size_t o_hb = o_zx + (size_t)CH * 524288;
  const size_t o_cs = o_hb + 131072;
  const size_t o_fl = o_cs + 524288;

  ushort* Wx  = (ushort*)(ws + o_Wx);
  ushort* Rs  = (ushort*)(ws + o_Rs);
  float*  bp  = (float*)(ws + o_bp);
  ushort* xsw = (ushort*)(ws + o_xsw);
  float*  zx  = (float*)(ws + o_zx);
  ushort* hb  = (ushort*)(ws + o_hb);
  float*  csv = (float*)(ws + o_cs);
  int*    fl  = (int*)(ws + o_fl);

  pack_weights<<<256, 256, 0, stream>>>(Wf, Wi, Wg, Wo, Rf, Ri, Rg, Ro,
                                        bfp, bip, bgp, bop, Wx, Rs, bp);
  swizzle_x<<<512, 256, 0, stream>>>(x, xsw);
  hipMemsetAsync(hb, 0, 131072, stream);  // h(t=0) = 0

  const int nch = 512 / CH;
  for (int c = 0; c < nch; ++c) {
    hipMemsetAsync(fl, 0, 256, stream);
    const int G = (CH < 16) ? CH : 16;
    zx_gemm<<<dim3(16, G), 512, 0, stream>>>(xsw, Wx, zx, c * CH, CH / G);
    rec_kernel<<<32, 512, 0, stream>>>(Rs, bp, zx, hb, csv, fl, dout, c * CH, CH);
  }
}

// Round 2
// 1786.818 us; speedup vs baseline: 2.1426x; 2.1426x over previous
//
#include <hip/hip_runtime.h>
#include <hip/hip_bf16.h>

typedef __attribute__((ext_vector_type(8))) short s16x8;
typedef __attribute__((ext_vector_type(4))) float f32x4;

__device__ __forceinline__ ushort f2bf(float x) {
  __hip_bfloat16 b = __float2bfloat16(x);
  return *reinterpret_cast<ushort*>(&b);
}

__device__ __forceinline__ float sigm_fast(float z) {
  return __builtin_amdgcn_rcpf(1.0f + __builtin_amdgcn_exp2f(z * -1.44269504088896f));
}

// ---------------------------------------------------------------------------
// K0: pack weights (unchanged from R1).
// Packed col p: gate = p&3, hcol = (p>>5)*8 + ((p>>4)&1)*4 + ((p&15)>>2).
// Wx[p][k] = W_gate[k][hcol]; Rs[p][k] = W_gate[512+k][hcol] + R_gate[k][hcol].
// ---------------------------------------------------------------------------
__global__ __launch_bounds__(256) void pack_weights(
    const float* __restrict__ Wf, const float* __restrict__ Wi,
    const float* __restrict__ Wg, const float* __restrict__ Wo,
    const float* __restrict__ Rf, const float* __restrict__ Ri,
    const float* __restrict__ Rg, const float* __restrict__ Ro,
    const float* __restrict__ bfp, const float* __restrict__ bip,
    const float* __restrict__ bgp, const float* __restrict__ bop,
    ushort* __restrict__ Wx, ushort* __restrict__ Rs, float* __restrict__ bp)
{
  const int p = blockIdx.x * 8 + (threadIdx.x >> 5);
  const int kk = (threadIdx.x & 31) * 16;
  const int gate = p & 3;
  const int hcol = (p >> 5) * 8 + ((p >> 4) & 1) * 4 + ((p & 15) >> 2);
  const float* W = (gate == 0) ? Wf : (gate == 1) ? Wi : (gate == 2) ? Wg : Wo;
  const float* R = (gate == 0) ? Rf : (gate == 1) ? Ri : (gate == 2) ? Rg : Ro;
  union { ushort u[16]; s16x8 v[2]; } wb, rb;
#pragma unroll
  for (int e = 0; e < 16; ++e) {
    const int k = kk + e;
    wb.u[e] = f2bf(W[(size_t)k * 512 + hcol]);
    rb.u[e] = f2bf(W[(size_t)(512 + k) * 512 + hcol] + R[(size_t)k * 512 + hcol]);
  }
  *(s16x8*)(Wx + (size_t)p * 512 + kk)     = wb.v[0];
  *(s16x8*)(Wx + (size_t)p * 512 + kk + 8) = wb.v[1];
  *(s16x8*)(Rs + (size_t)p * 512 + kk)     = rb.v[0];
  *(s16x8*)(Rs + (size_t)p * 512 + kk + 8) = rb.v[1];
  if ((threadIdx.x & 31) == 0) {
    const float* B = (gate == 0) ? bfp : (gate == 1) ? bip : (gate == 2) ? bgp : bop;
    bp[p] = B[hcol];
  }
}

// ---------------------------------------------------------------------------
// K1: pre-swizzle x into 16x16x32 A-fragment layout (unchanged from R1).
// ---------------------------------------------------------------------------
__global__ __launch_bounds__(256) void swizzle_x(
    const float* __restrict__ x, ushort* __restrict__ xsw)
{
  __shared__ ushort xl[64 * 520];
  const int t = blockIdx.x;
  const int tid = threadIdx.x;
  const float4* x4 = (const float4*)(x + (size_t)t * 32768);
#pragma unroll 4
  for (int j = 0; j < 32; ++j) {
    const int i4 = j * 256 + tid;
    const float4 v = x4[i4];
    const int base = i4 * 4;
    const int row = base >> 9;
    const int col = base & 511;
    ushort4 u;
    u.x = f2bf(v.x); u.y = f2bf(v.y); u.z = f2bf(v.z); u.w = f2bf(v.w);
    *(ushort4*)(&xl[row * 520 + col]) = u;
  }
  __syncthreads();
#pragma unroll 4
  for (int j = 0; j < 16; ++j) {
    const int F = j * 256 + tid;
    const int l = F & 63;
    const int kc = (F >> 6) & 15;
    const int mt = F >> 10;
    const int row = mt * 16 + (l & 15);
    const int k0 = kc * 32 + (l >> 4) * 8;
    const s16x8 v = *(const s16x8*)(&xl[row * 520 + k0]);
    *(s16x8*)(&xsw[((size_t)t * 4096 + F) * 8]) = v;
  }
}

// ---------------------------------------------------------------------------
// K2: Zx chunk GEMM (as R1 but launch_bounds(512,1) so Bg stays in VGPRs).
// ---------------------------------------------------------------------------
__global__ __launch_bounds__(512, 1) void zx_gemm(
    const ushort* __restrict__ xsw, const ushort* __restrict__ Wx,
    float* __restrict__ zx, int t0, int tcnt)
{
  __shared__ ushort lbuf[32768];
  const int pg = blockIdx.x;
  const int tgrp = blockIdx.y;
  const int tid = threadIdx.x;
  const int wid = tid >> 6;
  const int lane = tid & 63;
  const int mpair = wid >> 2;
  const int np = wid & 3;
  const int q = pg * 4 + np;
  const int l15 = lane & 15;
  const int hi = lane >> 4;

  s16x8 Bg[2][16];
#pragma unroll
  for (int nt = 0; nt < 2; ++nt)
#pragma unroll
    for (int kc = 0; kc < 16; ++kc)
      Bg[nt][kc] = *(const s16x8*)(Wx + (size_t)(q * 32 + nt * 16 + l15) * 512 + kc * 32 + hi * 8);

  for (int tt = 0; tt < tcnt; ++tt) {
    const int tl = tgrp * tcnt + tt;
    const int t = t0 + tl;
#pragma unroll
    for (int j = 0; j < 8; ++j) {
      const int fid = j * 512 + tid;
      *(s16x8*)(&lbuf[(size_t)fid * 8]) =
          *(const s16x8*)(xsw + ((size_t)t * 4096 + fid) * 8);
    }
    __syncthreads();
#pragma unroll
    for (int a = 0; a < 2; ++a) {
      const int mt = mpair * 2 + a;
      f32x4 acc0 = {0.f, 0.f, 0.f, 0.f};
      f32x4 acc1 = {0.f, 0.f, 0.f, 0.f};
#pragma unroll
      for (int kc = 0; kc < 16; ++kc) {
        const s16x8 af = *(const s16x8*)(&lbuf[((size_t)(mt * 16 + kc) * 64 + lane) * 8]);
        acc0 = __builtin_amdgcn_mfma_f32_16x16x32_bf16(af, Bg[0][kc], acc0, 0, 0, 0);
        acc1 = __builtin_amdgcn_mfma_f32_16x16x32_bf16(af, Bg[1][kc], acc1, 0, 0, 0);
      }
      float* o = zx + ((((size_t)tl * 4 + mt) * 64 + q) * 64 + lane) * 8;
      *(f32x4*)(o)     = acc0;
      *(f32x4*)(o + 4) = acc1;
    }
    __syncthreads();
  }
}

// ---------------------------------------------------------------------------
// K3: recurrence. 4 independent batch-groups (16 rows each) x 8 WGs x 8 waves.
// group = bid&3, member = bid>>2. Wave owns 32 packed cols (q = member*8+wid),
// all 16 rows. Rsum register-resident (launch_bounds(512,1) -> 256 VGPR).
// h published per-step to fresh slot via sc1 write-through relaxed atomics;
// group counter (relaxed agent atomicAdd) is the only sync. No cache fences.
// ---------------------------------------------------------------------------
__global__ __launch_bounds__(512, 1) void rec_kernel(
    const ushort* __restrict__ Rs, const float* __restrict__ bp,
    const float* __restrict__ zx, ushort* __restrict__ hbuf,
    float* __restrict__ csave, int* __restrict__ cnt,
    float* __restrict__ dout, int t0, int CH)
{
  __shared__ ushort hsl[8192];  // 16KB: [16 rows][512 cols], XOR-swizzled
  const int bid = blockIdx.x;
  const int g = bid & 3;
  const int tid = threadIdx.x;
  const int wid = tid >> 6;
  const int lane = tid & 63;
  const int q = (bid >> 2) * 8 + wid;   // packed col-group 0..63
  const int gate = lane & 3;
  const int l15 = lane & 15;
  const int hi = lane >> 4;

  // Rsum fragments: register-resident for the whole chunk (128 VGPR)
  s16x8 Brg[2][16];
#pragma unroll
  for (int nt = 0; nt < 2; ++nt)
#pragma unroll
    for (int kc = 0; kc < 16; ++kc)
      Brg[nt][kc] = *(const s16x8*)(Rs + (size_t)(q * 32 + nt * 16 + l15) * 512 + kc * 32 + hi * 8);

  const float b0 = bp[q * 32 + l15];
  const float b1 = bp[q * 32 + 16 + l15];

  float cst[2][4];
  float* csp = csave + ((size_t)(bid * 8 + wid) * 64 + lane) * 8;
  if (t0 == 0) {
#pragma unroll
    for (int i = 0; i < 2; ++i)
#pragma unroll
      for (int r = 0; r < 4; ++r) cst[i][r] = 0.0f;
  } else {
#pragma unroll
    for (int i = 0; i < 2; ++i)
#pragma unroll
      for (int r = 0; r < 4; ++r) cst[i][r] = csp[i * 4 + r];
  }

  const int srow = hi * 4 + gate;          // local output row 0..15
  const int hcol0 = q * 8 + (l15 >> 2);

  // LDS staging addresses (coop load: 32B per thread)
  const int crow = tid >> 5;               // 0..15
  const int cbyte = (tid & 31) * 32;
  const int cswz = (crow & 7) << 4;
  // A-frag ds_read address components
  const int abase = l15 * 1024 + hi * 16;
  const int aswz = (l15 & 7) << 4;

  int* const cptr = cnt + g * 64;

  // preload zx for step 0
  const float* zp = zx + ((((size_t)0 * 4 + g) * 64 + q) * 64 + lane) * 8;
  float4 z0 = *(const float4*)zp;
  float4 z1 = *(const float4*)(zp + 4);

  for (int tl = 0; tl < CH; ++tl) {
    const int t = t0 + tl;

    // --- wait for slot tl (all 8 members of this group published step t-1) ---
    if (tl > 0) {
      const int target = t * 8;
      while (__hip_atomic_load(cptr, __ATOMIC_RELAXED, __HIP_MEMORY_SCOPE_AGENT) < target) {}
      asm volatile("" ::: "memory");  // no hoisting of h loads above the spin
    }

    // --- stage h slot tl into LDS (swizzled) ---
    {
      const ushort* hsrc = hbuf + ((size_t)tl * 4 + g) * 8192;
      const s16x8 v0 = *(const s16x8*)(hsrc + crow * 512 + (cbyte >> 1));
      const s16x8 v1 = *(const s16x8*)(hsrc + crow * 512 + (cbyte >> 1) + 8);
      *(s16x8*)(&hsl[(crow * 1024 + (cbyte ^ cswz)) >> 1]) = v0;
      *(s16x8*)(&hsl[(crow * 1024 + ((cbyte + 16) ^ cswz)) >> 1]) = v1;
    }
    __syncthreads();

    // --- z = h @ Rsum (MFMA over K=512) ---
    f32x4 acc0 = {0.f, 0.f, 0.f, 0.f};
    f32x4 acc1 = {0.f, 0.f, 0.f, 0.f};
#pragma unroll
    for (int kc = 0; kc < 16; ++kc) {
      const s16x8 a = *(const s16x8*)(&hsl[((abase + kc * 64) ^ aswz) >> 1]);
      acc0 = __builtin_amdgcn_mfma_f32_16x16x32_bf16(a, Brg[0][kc], acc0, 0, 0, 0);
      acc1 = __builtin_amdgcn_mfma_f32_16x16x32_bf16(a, Brg[1][kc], acc1, 0, 0, 0);
    }

    // --- gates, cell update ---
    float h_out[2][4];
#pragma unroll
    for (int nt = 0; nt < 2; ++nt) {
#pragma unroll
      for (int r = 0; r < 4; ++r) {
        float z = (nt ? acc1[r] : acc0[r]);
        z += nt ? ((r == 0) ? z1.x : (r == 1) ? z1.y : (r == 2) ? z1.z : z1.w)
                : ((r == 0) ? z0.x : (r == 1) ? z0.y : (r == 2) ? z0.z : z0.w);
        z += nt ? b1 : b0;
        const float zz = (gate == 2) ? z + z : z;
        const float s = sigm_fast(zz);
        const float act = (gate == 2) ? (s + s - 1.0f) : s;
        const int ai = __float_as_int(act);
        const float fv = __int_as_float(__builtin_amdgcn_mov_dpp(ai, 0x00, 0xF, 0xF, true));
        const float iv = __int_as_float(__builtin_amdgcn_mov_dpp(ai, 0x55, 0xF, 0xF, true));
        const float gv = __int_as_float(__builtin_amdgcn_mov_dpp(ai, 0xAA, 0xF, 0xF, true));
        const float ov = __int_as_float(__builtin_amdgcn_mov_dpp(ai, 0xFF, 0xF, 0xF, true));
        const float cn = fmaf(fv, cst[nt][r], iv * gv);
        cst[nt][r] = cn;
        const float s2 = sigm_fast(cn + cn);
        h_out[nt][r] = ov * (s2 + s2 - 1.0f);
      }
    }

    // this lane's published values (row srow, cols hcol0 / hcol0+4)
    float hv[2], cv[2];
#pragma unroll
    for (int nt = 0; nt < 2; ++nt) {
      hv[nt] = (gate == 0) ? h_out[nt][0] : (gate == 1) ? h_out[nt][1]
             : (gate == 2) ? h_out[nt][2] : h_out[nt][3];
      cv[nt] = (gate == 0) ? cst[nt][0] : (gate == 1) ? cst[nt][1]
             : (gate == 2) ? cst[nt][2] : cst[nt][3];
    }

    // --- publish h(t+1) to slot tl+1: sc1 write-through, agent-visible ---
    {
      ushort* hn = hbuf + ((size_t)(tl + 1) * 4 + g) * 8192;
#pragma unroll
      for (int nt = 0; nt < 2; ++nt)
        __hip_atomic_store(&hn[srow * 512 + hcol0 + nt * 4], f2bf(hv[nt]),
                           __ATOMIC_RELAXED, __HIP_MEMORY_SCOPE_AGENT);
      if (tl == CH - 1) {  // duplicate into slot 0 for the next chunk launch
        ushort* h0 = hbuf + (size_t)g * 8192;
#pragma unroll
        for (int nt = 0; nt < 2; ++nt)
          h0[srow * 512 + hcol0 + nt * 4] = f2bf(hv[nt]);
      }
    }
    asm volatile("s_waitcnt vmcnt(0)" ::: "memory");
    __syncthreads();
    if (tid == 0)
      __hip_atomic_fetch_add(cptr, 1, __ATOMIC_RELAXED, __HIP_MEMORY_SCOPE_AGENT);

    // --- overlap region (hidden under other members' spins) ---
    if (tl + 1 < CH) {  // prefetch next zx fragment
      const float* zn = zx + ((((size_t)(tl + 1) * 4 + g) * 64 + q) * 64 + lane) * 8;
      z0 = *(const float4*)zn;
      z1 = *(const float4*)(zn + 4);
    }
    {
      const size_t drow = (size_t)(g * 16 + srow) * 512;
#pragma unroll
      for (int nt = 0; nt < 2; ++nt)
        dout[(size_t)t * 32768 + drow + hcol0 + nt * 4] = hv[nt];
      if (t == 511) {
#pragma unroll
        for (int nt = 0; nt < 2; ++nt) {
          dout[(size_t)16777216 + drow + hcol0 + nt * 4] = hv[nt];
          dout[(size_t)16809984 + drow + hcol0 + nt * 4] = cv[nt];
        }
      }
    }
  }

#pragma unroll
  for (int i = 0; i < 2; ++i)
#pragma unroll
    for (int r = 0; r < 4; ++r) csp[i * 4 + r] = cst[i][r];
}

// ---------------------------------------------------------------------------
extern "C" void kernel_launch(void* const* d_in, const int* in_sizes, int n_in,
                              void* d_out, int out_size, void* d_ws, size_t ws_size,
                              hipStream_t stream)
{
  const float* x   = (const float*)d_in[0];
  const float* Wf  = (const float*)d_in[1];
  const float* bfp = (const float*)d_in[2];
  const float* Wi  = (const float*)d_in[3];
  const float* bip = (const float*)d_in[4];
  const float* Wg  = (const float*)d_in[5];
  const float* bgp = (const float*)d_in[6];
  const float* Wo  = (const float*)d_in[7];
  const float* bop = (const float*)d_in[8];
  const float* Rf  = (const float*)d_in[9];
  const float* Ri  = (const float*)d_in[10];
  const float* Rg  = (const float*)d_in[11];
  const float* Ro  = (const float*)d_in[12];
  float* dout = (float*)d_out;
  char* ws = (char*)d_ws;

  const size_t o_Wx  = 0;
  const size_t o_Rs  = o_Wx + 2097152;
  const size_t o_bp  = o_Rs + 2097152;
  const size_t o_xsw = o_bp + 8192;
  const size_t o_zx  = o_xsw + 33554432;

  int CH = 64;
  while (CH > 4) {
    const size_t need = o_zx + (size_t)CH * 524288 + (size_t)(CH + 1) * 65536
                      + 524288 + 1024;
    if (need <= ws_size) break;
    CH >>= 1;
  }
  const size_t o_hb = o_zx + (size_t)CH * 524288;
  const size_t o_cs = o_hb + (size_t)(CH + 1) * 65536;
  const size_t o_fl = o_cs + 524288;

  ushort* Wx  = (ushort*)(ws + o_Wx);
  ushort* Rs  = (ushort*)(ws + o_Rs);
  float*  bp  = (float*)(ws + o_bp);
  ushort* xsw = (ushort*)(ws + o_xsw);
  float*  zx  = (float*)(ws + o_zx);
  ushort* hb  = (ushort*)(ws + o_hb);
  float*  csv = (float*)(ws + o_cs);
  int*    fl  = (int*)(ws + o_fl);

  pack_weights<<<256, 256, 0, stream>>>(Wf, Wi, Wg, Wo, Rf, Ri, Rg, Ro,
                                        bfp, bip, bgp, bop, Wx, Rs, bp);
  swizzle_x<<<512, 256, 0, stream>>>(x, xsw);
  hipMemsetAsync(hb, 0, 65536, stream);   // h(0) = 0 (slot 0, all groups)
  hipMemsetAsync(fl, 0, 1024, stream);    // group counters (monotone per run)

  const int nch = 512 / CH;
  for (int c = 0; c < nch; ++c) {
    const int G = (CH < 16) ? CH : 16;
    zx_gemm<<<dim3(16, G), 512, 0, stream>>>(xsw, Wx, zx, c * CH, CH / G);
    rec_kernel<<<32, 512, 0, stream>>>(Rs, bp, zx, hb, csv, fl, dout, c * CH, CH);
  }
}